// Round 1
// baseline (49.147 us; speedup 1.0000x reference)
//
#include <hip/hip_runtime.h>
#include <hip/hip_fp16.h>
#include <math.h>

#define NPOS 16384
#define NTOT 491520
#define NFEAT 768

typedef _Float16 h2 __attribute__((ext_vector_type(2)));

#if __has_builtin(__builtin_amdgcn_fdot2)
#define FDOT2(a, b, c) __builtin_amdgcn_fdot2((a), (b), (c), false)
#else
#define FDOT2(a, b, c) ((c) + (float)(a)[0] * (float)(b)[0] + (float)(a)[1] * (float)(b)[1])
#endif

// ---------------- prep kernel ----------------
// blocks 0..11 : W1 [64][768] f32 -> W1Th [768][64] fp16 (row f = 128B)
// block  12    : W2 [32][128] f32 -> W2T [64][32] half2, W2T[i][k] = (W2[k][2i], W2[k][2i+1])
// blocks 13..77: wstart[b] = lower_bound(white_indices, b), b in [0, NPOS]
// blocks 78..142: same for black
__global__ __launch_bounds__(256) void k_prep(
    const float* __restrict__ W1, const float* __restrict__ W2,
    const int* __restrict__ wi, const int* __restrict__ bi,
    __half* __restrict__ W1Th, __half2* __restrict__ W2T,
    int* __restrict__ wstart, int* __restrict__ bstart)
{
    __shared__ float tile[64][65];
    int bid = blockIdx.x, tid = threadIdx.x;
    if (bid < 12) {
        int f0 = bid * 64;
        int j = tid & 63, r0 = tid >> 6;
        for (int r = r0; r < 64; r += 4)
            tile[r][j] = W1[r * NFEAT + f0 + j];
        __syncthreads();
        int c = tid & 63, j0 = tid >> 6;
        for (int jj = j0; jj < 64; jj += 4)
            W1Th[(f0 + jj) * 64 + c] = __float2half(tile[c][jj]);
    } else if (bid == 12) {
        for (int x = tid; x < 64 * 32; x += 256) {
            int i = x >> 5, k = x & 31;
            W2T[x] = __floats2half2_rn(W2[k * 128 + 2 * i], W2[k * 128 + 2 * i + 1]);
        }
    } else if (bid < 78) {
        int b = (bid - 13) * 256 + tid;
        if (b <= NPOS) {
            int lo = 0, hi = NTOT;
            while (lo < hi) { int m = (lo + hi) >> 1; if (wi[m] < b) lo = m + 1; else hi = m; }
            wstart[b] = lo;
        }
    } else {
        int b = (bid - 78) * 256 + tid;
        if (b <= NPOS) {
            int lo = 0, hi = NTOT;
            while (lo < hi) { int m = (lo + hi) >> 1; if (bi[m] < b) lo = m + 1; else hi = m; }
            bstart[b] = lo;
        }
    }
}

// ---------------- gather kernel ----------------
// one wave per position; lane = accumulator component (64 per color)
__device__ __forceinline__ float seg_accum(const int* __restrict__ feats,
                                           const __half* __restrict__ W1Th,
                                           int s, int e, int lane)
{
    float a0 = 0.f, a1 = 0.f;
    for (int t = s; t < e; t += 64) {
        int idx = t + lane;
        int iv = (idx < e) ? feats[idx] : 0;  // one coalesced load = up to 64 indices
        int n = e - t; if (n > 64) n = 64;
        int i = 0;
        for (; i + 2 <= n; i += 2) {
            int f0 = __builtin_amdgcn_readlane(iv, i);      // SGPR broadcast, no DS
            int f1 = __builtin_amdgcn_readlane(iv, i + 1);
            a0 += __half2float(W1Th[f0 * 64 + lane]);
            a1 += __half2float(W1Th[f1 * 64 + lane]);
        }
        if (i < n) {
            int f0 = __builtin_amdgcn_readlane(iv, i);
            a0 += __half2float(W1Th[f0 * 64 + lane]);
        }
    }
    return a0 + a1;
}

__global__ __launch_bounds__(256) void k_gather(
    const int* __restrict__ wf, const int* __restrict__ bf,
    const __half* __restrict__ W1Th,
    const int* __restrict__ wstart, const int* __restrict__ bstart,
    const float* __restrict__ b1,
    __half* __restrict__ a1out)
{
    int tid = threadIdx.x;
    int wave = tid >> 6, lane = tid & 63;
    int pos = blockIdx.x * 4 + wave;
    float bias = b1[lane];

    int ws = wstart[pos], we = wstart[pos + 1];
    float accw = seg_accum(wf, W1Th, ws, we, lane);
    int bs = bstart[pos], be = bstart[pos + 1];
    float accb = seg_accum(bf, W1Th, bs, be, lane);

    float aw = fminf(fmaxf(accw + bias, 0.f), 1.f);
    float ab = fminf(fmaxf(accb + bias, 0.f), 1.f);
    a1out[pos * 128 + lane]      = __float2half(aw);
    a1out[pos * 128 + 64 + lane] = __float2half(ab);
}

// ---------------- head kernel ----------------
// one POSITION PER LANE: serial 128->32->1 MLP, W2 via wave-uniform scalar loads,
// a1 tile (64 rows x 256B = 16KB) stays in L1. No LDS, no cross-lane ops.
__global__ __launch_bounds__(64) void k_head(
    const h2* __restrict__ a1, const h2* __restrict__ W2T,
    const float* __restrict__ b2, const float* __restrict__ W3,
    const float* __restrict__ b3, float* __restrict__ out)
{
    int lane = threadIdx.x & 63;
    int pos = blockIdx.x * 64 + lane;

    float acc[32];
#pragma unroll
    for (int k = 0; k < 32; ++k) acc[k] = 0.f;

    const int4* aq = (const int4*)(a1 + pos * 64);  // 16B = 4 half2 pairs
#pragma unroll 4
    for (int i4 = 0; i4 < 16; ++i4) {
        int4 q = aq[i4];
        h2 p0 = __builtin_bit_cast(h2, q.x);
        h2 p1 = __builtin_bit_cast(h2, q.y);
        h2 p2 = __builtin_bit_cast(h2, q.z);
        h2 p3 = __builtin_bit_cast(h2, q.w);
        const h2* w0 = W2T + (i4 * 4 + 0) * 32;  // wave-uniform -> s_load
        const h2* w1 = W2T + (i4 * 4 + 1) * 32;
        const h2* w2 = W2T + (i4 * 4 + 2) * 32;
        const h2* w3 = W2T + (i4 * 4 + 3) * 32;
#pragma unroll
        for (int k = 0; k < 32; ++k) {
            acc[k] = FDOT2(p0, w0[k], acc[k]);
            acc[k] = FDOT2(p1, w1[k], acc[k]);
            acc[k] = FDOT2(p2, w2[k], acc[k]);
            acc[k] = FDOT2(p3, w3[k], acc[k]);
        }
    }

    float r = 0.f;
#pragma unroll
    for (int k = 0; k < 32; ++k) {
        float a2v = fminf(fmaxf(acc[k] + b2[k], 0.f), 1.f);
        r += a2v * W3[k];
    }
    float x = r + b3[0];
    out[pos] = 1.f / (1.f + expf(-x));
}

extern "C" void kernel_launch(void* const* d_in, const int* in_sizes, int n_in,
                              void* d_out, int out_size, void* d_ws, size_t ws_size,
                              hipStream_t stream) {
    const int*   wf = (const int*)d_in[0];
    const int*   wi = (const int*)d_in[1];
    const int*   bf = (const int*)d_in[2];
    const int*   bi = (const int*)d_in[3];
    const float* W1 = (const float*)d_in[4];
    const float* b1 = (const float*)d_in[5];
    const float* W2 = (const float*)d_in[6];
    const float* b2 = (const float*)d_in[7];
    const float* W3 = (const float*)d_in[8];
    const float* b3 = (const float*)d_in[9];
    float* out = (float*)d_out;

    char* ws = (char*)d_ws;
    __half*  a1    = (__half*)ws;                                   // 16384*128*2 = 4,194,304 B
    __half*  W1Th  = (__half*)(ws + 4194304);                       // 98,304 B
    __half2* W2T   = (__half2*)(ws + 4194304 + 98304);              // 8,192 B
    int*     wstart = (int*)(ws + 4194304 + 98304 + 8192);          // 65,540 B
    int*     bstart = (int*)(ws + 4194304 + 98304 + 8192 + 65540);  // 65,540 B

    k_prep  <<<143, 256, 0, stream>>>(W1, W2, wi, bi, W1Th, W2T, wstart, bstart);
    k_gather<<<NPOS / 4, 256, 0, stream>>>(wf, bf, W1Th, wstart, bstart, b1, a1);
    k_head  <<<NPOS / 64, 64, 0, stream>>>((const h2*)a1, (const h2*)W2T, b2, W3, b3, out);
}

// Round 2
// 48.009 us; speedup vs baseline: 1.0237x; 1.0237x over previous
//
#include <hip/hip_runtime.h>
#include <hip/hip_fp16.h>
#include <math.h>

#define NPOS 16384
#define NTOT 491520
#define NFEAT 768

typedef _Float16 h2 __attribute__((ext_vector_type(2)));

__device__ __forceinline__ int imin(int a, int b) { return a < b ? a : b; }

#if __has_builtin(__builtin_amdgcn_fdot2)
#define FDOT2(a, b, c) __builtin_amdgcn_fdot2((a), (b), (c), false)
#else
#define FDOT2(a, b, c) ((c) + (float)(a)[0] * (float)(b)[0] + (float)(a)[1] * (float)(b)[1])
#endif

__device__ __forceinline__ h2 toh2(__half2 x) { return __builtin_bit_cast(h2, x); }

// ---------------- prep kernel ----------------
// blocks 0..11 : W1 [64][768] f32 -> W1Th [768][64] fp16 (row f = 128B)
// block  12    : W2 [32][128] f32 -> W2T [64][32] half2: W2T[jj*32+k] = (W2[k][2jj], W2[k][2jj+1])
// blocks 13..44 : white segment starts via linear scatter over sorted indices
// blocks 45..76 : black segment starts
__global__ __launch_bounds__(256) void k_prep(
    const float* __restrict__ W1, const float* __restrict__ W2,
    const int* __restrict__ wi, const int* __restrict__ bi,
    __half* __restrict__ W1Th, __half2* __restrict__ W2T,
    int* __restrict__ wstart, int* __restrict__ bstart)
{
    __shared__ float tile[64][65];
    int bid = blockIdx.x, tid = threadIdx.x;
    if (bid < 12) {
        int f0 = bid * 64;
        int j = tid & 63, r0 = tid >> 6;
        for (int r = r0; r < 64; r += 4)
            tile[r][j] = W1[r * NFEAT + f0 + j];
        __syncthreads();
        int c = tid & 63, j0 = tid >> 6;
        for (int jj = j0; jj < 64; jj += 4)
            W1Th[(f0 + jj) * 64 + c] = __float2half(tile[c][jj]);
    } else if (bid == 12) {
        for (int x = tid; x < 64 * 32; x += 256) {
            int i = x >> 5, k = x & 31;
            W2T[x] = __floats2half2_rn(W2[k * 128 + 2 * i], W2[k * 128 + 2 * i + 1]);
        }
    } else if (bid < 45) {
        // white: start[b] = lower_bound(wi, b). Linear scatter: coalesced, no dep chains.
        for (int t = (bid - 13) * 256 + tid; t < NTOT; t += 32 * 256) {
            int v = wi[t];
            int p = (t == 0) ? -1 : wi[t - 1];
            for (int b = p + 1; b <= v; ++b) wstart[b] = t;
            if (t == NTOT - 1)
                for (int b = v + 1; b <= NPOS; ++b) wstart[b] = NTOT;
        }
    } else {
        for (int t = (bid - 45) * 256 + tid; t < NTOT; t += 32 * 256) {
            int v = bi[t];
            int p = (t == 0) ? -1 : bi[t - 1];
            for (int b = p + 1; b <= v; ++b) bstart[b] = t;
            if (t == NTOT - 1)
                for (int b = v + 1; b <= NPOS; ++b) bstart[b] = NTOT;
        }
    }
}

// ---------------- gather kernel ----------------
// one wave per position; lanes 0-31 accumulate even-indexed features, lanes 32-63 odd,
// each lane holds component pair (2s, 2s+1) as f32. dword (half2) row loads: 2 rows/inst.
__global__ __launch_bounds__(256) void k_gather(
    const int* __restrict__ wf, const int* __restrict__ bf,
    const __half2* __restrict__ W1T2,
    const int* __restrict__ wstart, const int* __restrict__ bstart,
    const float* __restrict__ b1,
    __half2* __restrict__ a1out)
{
    int tid = threadIdx.x;
    int wave = tid >> 6, lane = tid & 63;
    int pos = blockIdx.x * 4 + wave;
    int sub = lane & 31;
    bool hi = lane >= 32;

    int ws = wstart[pos], we = wstart[pos + 1];
    int bs = bstart[pos], be = bstart[pos + 1];

    float wA0 = 0.f, wA1 = 0.f, wB0 = 0.f, wB1 = 0.f;
    float bA0 = 0.f, bA1 = 0.f, bB0 = 0.f, bB1 = 0.f;

    // prefetch first index chunk of BOTH colors (black's latency hides under white compute)
    int ivw = wf[imin(ws + lane, NTOT - 1)];
    int ivb = bf[imin(bs + lane, NTOT - 1)];

    auto process = [&](int iv, int n, float& A0, float& A1, float& B0, float& B1) {
        int i = 0;
        for (; i + 4 <= n; i += 4) {
            int f0 = __builtin_amdgcn_readlane(iv, i);
            int f1 = __builtin_amdgcn_readlane(iv, i + 1);
            int f2 = __builtin_amdgcn_readlane(iv, i + 2);
            int f3 = __builtin_amdgcn_readlane(iv, i + 3);
            __half2 va = W1T2[(hi ? f1 : f0) * 32 + sub];   // 2 independent loads issued
            __half2 vb = W1T2[(hi ? f3 : f2) * 32 + sub];   // before consumption
            float2 xa = __half22float2(va);
            float2 xb = __half22float2(vb);
            A0 += xa.x; A1 += xa.y;
            B0 += xb.x; B1 += xb.y;
        }
        if (i + 2 <= n) {
            int f0 = __builtin_amdgcn_readlane(iv, i);
            int f1 = __builtin_amdgcn_readlane(iv, i + 1);
            float2 xa = __half22float2(W1T2[(hi ? f1 : f0) * 32 + sub]);
            A0 += xa.x; A1 += xa.y;
            i += 2;
        }
        if (i < n) {
            int f0 = __builtin_amdgcn_readlane(iv, i);
            float2 xa = __half22float2(W1T2[f0 * 32 + sub]);
            if (!hi) { A0 += xa.x; A1 += xa.y; }   // last (even) row belongs to low half only
        }
    };

    process(ivw, imin(we - ws, 64), wA0, wA1, wB0, wB1);
    process(ivb, imin(be - bs, 64), bA0, bA1, bB0, bB1);
    for (int t = ws + 64; t < we; t += 64) {   // rare: segment > 64
        int iv = wf[imin(t + lane, NTOT - 1)];
        process(iv, imin(we - t, 64), wA0, wA1, wB0, wB1);
    }
    for (int t = bs + 64; t < be; t += 64) {
        int iv = bf[imin(t + lane, NTOT - 1)];
        process(iv, imin(be - t, 64), bA0, bA1, bB0, bB1);
    }

    float w0 = wA0 + wB0, w1 = wA1 + wB1;
    float k0 = bA0 + bB0, k1 = bA1 + bB1;
    // merge even/odd halves: both halves end with the full component-pair sums
    w0 += __shfl_xor(w0, 32);
    w1 += __shfl_xor(w1, 32);
    k0 += __shfl_xor(k0, 32);
    k1 += __shfl_xor(k1, 32);

    float2 bias = ((const float2*)b1)[sub];
    float u0 = (hi ? k0 : w0) + bias.x;
    float u1 = (hi ? k1 : w1) + bias.y;
    u0 = fminf(fmaxf(u0, 0.f), 1.f);
    u1 = fminf(fmaxf(u1, 0.f), 1.f);
    // row layout [pos][64 half2]: lanes 0-31 write white pairs, 32-63 black pairs -> 256B coalesced
    a1out[pos * 64 + (hi ? 32 : 0) + sub] = __floats2half2_rn(u0, u1);
}

// ---------------- head kernel ----------------
// one position per lane, k-dim split across 2 waves (k0 wave-uniform via readfirstlane ->
// W2T/b2/W3 stay scalar loads). a1 tile L1-resident; partials combined through 512B LDS.
__global__ __launch_bounds__(128) void k_head(
    const uint4* __restrict__ a1q, const __half2* __restrict__ W2T,
    const float* __restrict__ b2, const float* __restrict__ W3,
    const float* __restrict__ b3, float* __restrict__ out)
{
    int tid = threadIdx.x;
    int w = tid >> 6, lane = tid & 63;
    int pos = blockIdx.x * 64 + lane;
    int k0 = __builtin_amdgcn_readfirstlane(w * 16);   // wave-uniform -> s_load addresses

    __shared__ float rpart[2][64];

    float acc[16];
#pragma unroll
    for (int k = 0; k < 16; ++k) acc[k] = 0.f;

    const uint4* aq = a1q + pos * 16;
#pragma unroll
    for (int i4 = 0; i4 < 16; ++i4) {
        uint4 q = aq[i4];
        h2 p0 = __builtin_bit_cast(h2, q.x);
        h2 p1 = __builtin_bit_cast(h2, q.y);
        h2 p2 = __builtin_bit_cast(h2, q.z);
        h2 p3 = __builtin_bit_cast(h2, q.w);
        const __half2* w0r = W2T + (i4 * 4 + 0) * 32 + k0;
        const __half2* w1r = W2T + (i4 * 4 + 1) * 32 + k0;
        const __half2* w2r = W2T + (i4 * 4 + 2) * 32 + k0;
        const __half2* w3r = W2T + (i4 * 4 + 3) * 32 + k0;
#pragma unroll
        for (int k = 0; k < 16; ++k) {
            acc[k] = FDOT2(p0, toh2(w0r[k]), acc[k]);
            acc[k] = FDOT2(p1, toh2(w1r[k]), acc[k]);
            acc[k] = FDOT2(p2, toh2(w2r[k]), acc[k]);
            acc[k] = FDOT2(p3, toh2(w3r[k]), acc[k]);
        }
    }

    float r = 0.f;
#pragma unroll
    for (int k = 0; k < 16; ++k) {
        float a2v = fminf(fmaxf(acc[k] + b2[k0 + k], 0.f), 1.f);
        r += a2v * W3[k0 + k];
    }
    rpart[w][lane] = r;
    __syncthreads();
    if (w == 0) {
        float x = rpart[0][lane] + rpart[1][lane] + b3[0];
        out[pos] = 1.f / (1.f + expf(-x));
    }
}

extern "C" void kernel_launch(void* const* d_in, const int* in_sizes, int n_in,
                              void* d_out, int out_size, void* d_ws, size_t ws_size,
                              hipStream_t stream) {
    const int*   wf = (const int*)d_in[0];
    const int*   wi = (const int*)d_in[1];
    const int*   bf = (const int*)d_in[2];
    const int*   bi = (const int*)d_in[3];
    const float* W1 = (const float*)d_in[4];
    const float* b1 = (const float*)d_in[5];
    const float* W2 = (const float*)d_in[6];
    const float* b2 = (const float*)d_in[7];
    const float* W3 = (const float*)d_in[8];
    const float* b3 = (const float*)d_in[9];
    float* out = (float*)d_out;

    char* ws = (char*)d_ws;
    __half*  a1    = (__half*)ws;                                   // 16384*128*2 = 4,194,304 B
    __half*  W1Th  = (__half*)(ws + 4194304);                       // 98,304 B
    __half2* W2T   = (__half2*)(ws + 4194304 + 98304);              // 8,192 B
    int*     wstart = (int*)(ws + 4194304 + 98304 + 8192);          // 65,540 B
    int*     bstart = (int*)(ws + 4194304 + 98304 + 8192 + 65540);  // 65,540 B

    k_prep  <<<77, 256, 0, stream>>>(W1, W2, wi, bi, W1Th, W2T, wstart, bstart);
    k_gather<<<NPOS / 4, 256, 0, stream>>>(wf, bf, (const __half2*)W1Th, wstart, bstart, b1,
                                           (__half2*)a1);
    k_head  <<<NPOS / 64, 128, 0, stream>>>((const uint4*)a1, W2T, b2, W3, b3, out);
}

// Round 3
// 32.480 us; speedup vs baseline: 1.5131x; 1.4781x over previous
//
#include <hip/hip_runtime.h>
#include <hip/hip_fp16.h>
#include <math.h>

#define NPOS 16384
#define NTOT 491520
#define NFEAT 768
#define DUMMY 768   // extra zero row in W1Th

typedef _Float16 h2 __attribute__((ext_vector_type(2)));

__device__ __forceinline__ int imin(int a, int b) { return a < b ? a : b; }
__device__ __forceinline__ float clamp01(float x) { return fminf(fmaxf(x, 0.f), 1.f); }

#if __has_builtin(__builtin_amdgcn_fdot2)
#define FDOT2(a, b, c) __builtin_amdgcn_fdot2((a), (b), (c), false)
#else
#define FDOT2(a, b, c) ((c) + (float)(a)[0] * (float)(b)[0] + (float)(a)[1] * (float)(b)[1])
#endif

__device__ __forceinline__ h2 toh2(__half2 x) { return __builtin_bit_cast(h2, x); }

// ---------------- prep kernel ----------------
// blocks 0..11  : W1 [64][768] f32 -> W1Th [769][64] fp16 (row f = 128B)
// block  12     : W2 [32][128] f32 -> W2T [64][32] half2 + zero row 768 of W1Th
// blocks 13..76 : white segment starts (linear scatter over sorted indices)
// blocks 77..140: black segment starts
__global__ __launch_bounds__(256) void k_prep(
    const float* __restrict__ W1, const float* __restrict__ W2,
    const int* __restrict__ wi, const int* __restrict__ bi,
    __half* __restrict__ W1Th, __half2* __restrict__ W2T,
    int* __restrict__ wstart, int* __restrict__ bstart)
{
    __shared__ float tile[64][65];
    int bid = blockIdx.x, tid = threadIdx.x;
    if (bid < 12) {
        int f0 = bid * 64;
        int j = tid & 63, r0 = tid >> 6;
        for (int r = r0; r < 64; r += 4)
            tile[r][j] = W1[r * NFEAT + f0 + j];
        __syncthreads();
        int c = tid & 63, j0 = tid >> 6;
        for (int jj = j0; jj < 64; jj += 4)
            W1Th[(f0 + jj) * 64 + c] = __float2half(tile[c][jj]);
    } else if (bid == 12) {
        for (int x = tid; x < 64 * 32; x += 256) {
            int i = x >> 5, k = x & 31;
            W2T[x] = __floats2half2_rn(W2[k * 128 + 2 * i], W2[k * 128 + 2 * i + 1]);
        }
        if (tid < 64) W1Th[DUMMY * 64 + tid] = __float2half(0.f);
    } else if (bid < 77) {
        // wstart[b] = lower_bound(wi, b): coalesced linear scatter, no dep chains
        for (int t = (bid - 13) * 256 + tid; t < NTOT; t += 64 * 256) {
            int v = wi[t];
            int p = (t == 0) ? -1 : wi[t - 1];
            for (int b = p + 1; b <= v; ++b) wstart[b] = t;
            if (t == NTOT - 1)
                for (int b = v + 1; b <= NPOS; ++b) wstart[b] = NTOT;
        }
    } else {
        for (int t = (bid - 77) * 256 + tid; t < NTOT; t += 64 * 256) {
            int v = bi[t];
            int p = (t == 0) ? -1 : bi[t - 1];
            for (int b = p + 1; b <= v; ++b) bstart[b] = t;
            if (t == NTOT - 1)
                for (int b = v + 1; b <= NPOS; ++b) bstart[b] = NTOT;
        }
    }
}

// ---------------- fused gather + head ----------------
// One wave per position. Gather: 4 rows per dwordx2 load (4 lane-groups of 16),
// row indices via per-wave LDS broadcast, dummy zero-row pads segments to x4.
// Head: a1 staged in 256B LDS, 32 v_dot2 per lane + shuffle reduces, no extra kernel.
__global__ __launch_bounds__(256) void k_fused(
    const int* __restrict__ wf, const int* __restrict__ bf,
    const uint2* __restrict__ W1q,      // [769][16] uint2 (fp16 rows, 128B)
    const __half2* __restrict__ W2T,    // [64][32] half2
    const int* __restrict__ wstart, const int* __restrict__ bstart,
    const float4* __restrict__ b1q,     // b1 as 16 float4
    const float* __restrict__ b2, const float* __restrict__ W3,
    const float* __restrict__ b3, float* __restrict__ out)
{
    __shared__ int ivs[4][2][64];
    __shared__ __half2 a1s[4][64];      // 128 halfs per wave

    int tid = threadIdx.x;
    int wave = tid >> 6, lane = tid & 63;
    int pos = blockIdx.x * 4 + wave;
    int g = lane >> 4, k = lane & 15;

    int ws_ = wstart[pos], we = wstart[pos + 1];
    int bs_ = bstart[pos], be = bstart[pos + 1];

    {
        int iw = ws_ + lane, ib = bs_ + lane;
        ivs[wave][0][lane] = (iw < we) ? wf[iw] : DUMMY;
        ivs[wave][1][lane] = (ib < be) ? bf[ib] : DUMMY;
    }
    __syncthreads();

    float wa0 = 0.f, wa1 = 0.f, wa2 = 0.f, wa3 = 0.f;
    float ba0 = 0.f, ba1 = 0.f, ba2 = 0.f, ba3 = 0.f;

    int ngw = (imin(we - ws_, 64) + 3) >> 2;
    int ngb = (imin(be - bs_, 64) + 3) >> 2;
    const int* ivw = &ivs[wave][0][0];
    const int* ivb = &ivs[wave][1][0];

    for (int q = 0; q < ngw; ++q) {
        int f = ivw[q * 4 + g];                      // ds_read broadcast per 16-lane group
        uint2 d = W1q[f * 16 + k];                   // 4 rows per wave-instruction
        h2 lo = __builtin_bit_cast(h2, d.x), hi = __builtin_bit_cast(h2, d.y);
        wa0 += (float)lo[0]; wa1 += (float)lo[1];
        wa2 += (float)hi[0]; wa3 += (float)hi[1];
    }
    for (int q = 0; q < ngb; ++q) {
        int f = ivb[q * 4 + g];
        uint2 d = W1q[f * 16 + k];
        h2 lo = __builtin_bit_cast(h2, d.x), hi = __builtin_bit_cast(h2, d.y);
        ba0 += (float)lo[0]; ba1 += (float)lo[1];
        ba2 += (float)hi[0]; ba3 += (float)hi[1];
    }

    // rare tails (segment > 64): readlane + cndmask path, same dummy padding
    auto tail = [&](const int* __restrict__ feats, int t, int e,
                    float& A0, float& A1, float& A2, float& A3) {
        int idx = t + lane;
        int iv = (idx < e) ? feats[idx] : DUMMY;
        int ng = (imin(e - t, 64) + 3) >> 2;
        for (int q = 0; q < ng; ++q) {
            int f0 = __builtin_amdgcn_readlane(iv, q * 4 + 0);
            int f1 = __builtin_amdgcn_readlane(iv, q * 4 + 1);
            int f2 = __builtin_amdgcn_readlane(iv, q * 4 + 2);
            int f3 = __builtin_amdgcn_readlane(iv, q * 4 + 3);
            int s01 = (g & 1) ? f1 : f0;
            int s23 = (g & 1) ? f3 : f2;
            int f = (g & 2) ? s23 : s01;
            uint2 d = W1q[f * 16 + k];
            h2 lo = __builtin_bit_cast(h2, d.x), hi = __builtin_bit_cast(h2, d.y);
            A0 += (float)lo[0]; A1 += (float)lo[1];
            A2 += (float)hi[0]; A3 += (float)hi[1];
        }
    };
    for (int t = ws_ + 64; t < we; t += 64) tail(wf, t, we, wa0, wa1, wa2, wa3);
    for (int t = bs_ + 64; t < be; t += 64) tail(bf, t, be, ba0, ba1, ba2, ba3);

    // reduce across the 4 lane-groups (xor 16, 32)
    wa0 += __shfl_xor(wa0, 16); wa0 += __shfl_xor(wa0, 32);
    wa1 += __shfl_xor(wa1, 16); wa1 += __shfl_xor(wa1, 32);
    wa2 += __shfl_xor(wa2, 16); wa2 += __shfl_xor(wa2, 32);
    wa3 += __shfl_xor(wa3, 16); wa3 += __shfl_xor(wa3, 32);
    ba0 += __shfl_xor(ba0, 16); ba0 += __shfl_xor(ba0, 32);
    ba1 += __shfl_xor(ba1, 16); ba1 += __shfl_xor(ba1, 32);
    ba2 += __shfl_xor(ba2, 16); ba2 += __shfl_xor(ba2, 32);
    ba3 += __shfl_xor(ba3, 16); ba3 += __shfl_xor(ba3, 32);

    // bias + hardtanh + pack to fp16, stage a1 row (128 halfs) in LDS
    float4 bb = b1q[k];
    if (lane < 32) {
        __half2 p0, p1;
        if (g == 0) {
            p0 = __floats2half2_rn(clamp01(wa0 + bb.x), clamp01(wa1 + bb.y));
            p1 = __floats2half2_rn(clamp01(wa2 + bb.z), clamp01(wa3 + bb.w));
        } else {
            p0 = __floats2half2_rn(clamp01(ba0 + bb.x), clamp01(ba1 + bb.y));
            p1 = __floats2half2_rn(clamp01(ba2 + bb.z), clamp01(ba3 + bb.w));
        }
        a1s[wave][g * 32 + k * 2]     = p0;
        a1s[wave][g * 32 + k * 2 + 1] = p1;
    }
    __syncthreads();

    // head: lane = (j = output 0..31, h = i-half); 32 fdot2 each
    int j = lane & 31, h = lane >> 5;
    const __half2* a1row = &a1s[wave][h * 32];
    const __half2* wrow = W2T + h * 32 * 32 + j;
    float acc = 0.f;
#pragma unroll
    for (int t = 0; t < 32; ++t)
        acc = FDOT2(toh2(a1row[t]), toh2(wrow[t * 32]), acc);
    acc += __shfl_xor(acc, 32);

    float a2v = clamp01(acc + b2[j]);
    float p = a2v * W3[j];
    p += __shfl_xor(p, 16);
    p += __shfl_xor(p, 8);
    p += __shfl_xor(p, 4);
    p += __shfl_xor(p, 2);
    p += __shfl_xor(p, 1);
    if (lane == 0) {
        float x = p + b3[0];
        out[pos] = 1.f / (1.f + expf(-x));
    }
}

extern "C" void kernel_launch(void* const* d_in, const int* in_sizes, int n_in,
                              void* d_out, int out_size, void* d_ws, size_t ws_size,
                              hipStream_t stream) {
    const int*   wf = (const int*)d_in[0];
    const int*   wi = (const int*)d_in[1];
    const int*   bf = (const int*)d_in[2];
    const int*   bi = (const int*)d_in[3];
    const float* W1 = (const float*)d_in[4];
    const float* b1 = (const float*)d_in[5];
    const float* W2 = (const float*)d_in[6];
    const float* b2 = (const float*)d_in[7];
    const float* W3 = (const float*)d_in[8];
    const float* b3 = (const float*)d_in[9];
    float* out = (float*)d_out;

    char* ws = (char*)d_ws;
    __half*  W1Th   = (__half*)ws;                      // 769*64*2 = 98,432 B
    __half2* W2T    = (__half2*)(ws + 98560);           // 8,192 B
    int*     wstart = (int*)(ws + 106752);              // 65,540 B
    int*     bstart = (int*)(ws + 172544);              // 65,540 B

    k_prep <<<141, 256, 0, stream>>>(W1, W2, wi, bi, W1Th, W2T, wstart, bstart);
    k_fused<<<NPOS / 4, 256, 0, stream>>>(wf, bf, (const uint2*)W1Th, W2T,
                                          wstart, bstart, (const float4*)b1,
                                          b2, W3, b3, out);
}